// Round 6
// baseline (343.595 us; speedup 1.0000x reference)
//
#include <hip/hip_runtime.h>
#include <math.h>

// Problem constants (fixed by the reference).
constexpr int kN  = 250000;
constexpr int kC  = 32;
constexpr int kFC = 16;
constexpr int kFN = 16;
constexpr int kV  = 64;
constexpr int kBlock = 1024;

// Half-table row stride in dwords: 16 classes + 2 pad (72B rows; b128 start
// bank (18r+4q)%32 spreads over 16 even banks).
constexpr int kRowDw = 18;

// ws layout (dwords):
//   [0..1023]    {A=-0.5/s^2, B=m/s^2} interleaved per (c,f)
//   [1024..1055] K_c (incl. folded C = -0.5 m^2/s^2 and log-class-prior)
//   [1088 ..]    split-path result arrays:
//     best  [2][kN] at 1088
//     second[2][kN] at 1088 + 2*kN
//     besti [2][kN] at 1088 + 4*kN   (stored as int)
constexpr int    kOffRes      = 1088;
constexpr size_t kWsNeedSplit = (size_t)(kOffRes + 6 * kN) * 4;  // ~6.0 MB

// ---------------------------------------------------------------------------
// Round-5 result: spill fixed (VGPR 60, WRITE_SIZE clean) but 71 us ==
// round-1 time despite 4x fewer LDS insts -> not throughput-bound on any
// pipe; latency-bound at 16 waves/CU (144KB table = 1 WG/CU).
// Round-6: CLASS-SPLIT. Each block stages a 16-class half-table (72KB) ->
// 2 blocks/CU = 32 waves/CU, half the per-thread dependency chain. Two
// blocks per sample-chunk write per-half top-2; a merge kernel combines.
//
// Numerics: per-class T_c has the SAME op order as round 5 ->
// bit-identical scores; top2(32) = merge(top2(16), top2(16)) exactly,
// half-0 preferred on ties (= lowest-index first-max semantics).
// Accept iff T_best >= -86 AND top-2 gap >= 8e-3 (6x-validated bound:
// approx error B <= 2e-3, gap >= 4B). On reject: FULL exact reference
// sequence over all 32 classes (validated; handles deep underflow /
// denormals / all-zero ties -> first max).
// ---------------------------------------------------------------------------

__global__ __launch_bounds__(256) void nbc_prep(
    const float* __restrict__ class_probs,
    const float* __restrict__ means,
    const float* __restrict__ stds,
    float* __restrict__ ws)
{
    const int t = threadIdx.x;
    const float two_pi = 2.0f * (float)M_PI;
    for (int i = t; i < kC * kFN; i += 256) {
        float m  = means[i];
        float s  = stds[i];
        float rs = 1.0f / s;
        ws[2 * i]     = -0.5f * rs * rs;        // A
        ws[2 * i + 1] = m * rs * rs;            // B
    }
    if (t < kC) {
        float k = logf(class_probs[t]);
        for (int f = 0; f < kFN; ++f) {
            float s  = stds[t * kFN + f];
            float m  = means[t * kFN + f];
            float rs = 1.0f / s;
            k += logf(1.0f / (two_pi * (s * s)));
            k += -0.5f * (m * rs) * (m * rs);   // C folded into K
        }
        ws[1024 + t] = k;
    }
}

// ---- split path: one block = (sample-chunk, class-half) ----
__global__ __launch_bounds__(kBlock) void nbc_half(
    const int*   __restrict__ X_cat,
    const float* __restrict__ X_num,
    const float* __restrict__ cat_probs,
    float* __restrict__ ws)
{
    __shared__ float lcat[1024 * kRowDw];   // [r=(f,v)][class-in-half], 72 KiB

    const int chunk = blockIdx.x >> 1;
    const int half  = blockIdx.x & 1;
    const int tid   = threadIdx.x;
    const int n     = chunk * kBlock + tid;
    const bool active = (n < kN);

    // per-sample inputs first (latency hides under staging)
    unsigned pack[4];
    float    x[kFN];
    if (active) {
        const int4* p4 = reinterpret_cast<const int4*>(X_cat + (size_t)n * kFC);
        int4 a0 = p4[0], a1 = p4[1], a2 = p4[2], a3 = p4[3];
        pack[0] = (unsigned)a0.x | ((unsigned)a0.y << 8) |
                  ((unsigned)a0.z << 16) | ((unsigned)a0.w << 24);
        pack[1] = (unsigned)a1.x | ((unsigned)a1.y << 8) |
                  ((unsigned)a1.z << 16) | ((unsigned)a1.w << 24);
        pack[2] = (unsigned)a2.x | ((unsigned)a2.y << 8) |
                  ((unsigned)a2.z << 16) | ((unsigned)a2.w << 24);
        pack[3] = (unsigned)a3.x | ((unsigned)a3.y << 8) |
                  ((unsigned)a3.z << 16) | ((unsigned)a3.w << 24);

        const float4* q4 = reinterpret_cast<const float4*>(X_num + (size_t)n * kFN);
        float4 b0 = q4[0], b1 = q4[1], b2 = q4[2], b3 = q4[3];
        x[0]=b0.x;  x[1]=b0.y;  x[2]=b0.z;  x[3]=b0.w;
        x[4]=b1.x;  x[5]=b1.y;  x[6]=b1.z;  x[7]=b1.w;
        x[8]=b2.x;  x[9]=b2.y;  x[10]=b2.z; x[11]=b2.w;
        x[12]=b3.x; x[13]=b3.y; x[14]=b3.z; x[15]=b3.w;
    } else {
        pack[0] = pack[1] = pack[2] = pack[3] = 0u;
        #pragma unroll
        for (int f = 0; f < kFN; ++f) x[f] = 0.0f;
    }

    // stage this half's log-table: thread t = row r; 16 logf; 4 b128 writes.
    // cat_probs[(half*16 + cl)*1024 + r] is coalesced across t.
    {
        #pragma unroll
        for (int q = 0; q < 4; ++q) {
            float4 w;
            w.x = logf(cat_probs[(size_t)((half << 4) + q * 4 + 0) * 1024 + tid]);
            w.y = logf(cat_probs[(size_t)((half << 4) + q * 4 + 1) * 1024 + tid]);
            w.z = logf(cat_probs[(size_t)((half << 4) + q * 4 + 2) * 1024 + tid]);
            w.w = logf(cat_probs[(size_t)((half << 4) + q * 4 + 3) * 1024 + tid]);
            *reinterpret_cast<float4*>(lcat + tid * kRowDw + q * 4) = w;
        }
    }
    __syncthreads();

    if (!active) return;

    int rowdw[kFC];
    #pragma unroll
    for (int f = 0; f < kFC; ++f) {
        const int v = (pack[f >> 2] >> ((f & 3) * 8)) & 63;
        rowdw[f] = ((f << 6) + v) * kRowDw;
    }

    const float2* __restrict__ P = reinterpret_cast<const float2*>(ws); // {A,B}
    const float*  __restrict__ K = ws + 1024;

    float best = -INFINITY, second = -INFINITY;
    int   besti = 0;

    // 4 class-groups of 4 within this half; only acc[4] live at a time.
    #pragma unroll 1
    for (int grp = 0; grp < 4; ++grp) {
        const int cbase = (half << 4) + (grp << 2);   // global class base
        float acc[4];

        #pragma unroll
        for (int j = 0; j < 4; ++j) {
            const int c = cbase + j;                  // wave-uniform
            float a = K[c];
            #pragma unroll
            for (int f = 0; f < kFN; ++f) {
                float2 p = P[(c << 4) + f];
                a = fmaf(x[f], fmaf(x[f], p.x, p.y), a);
            }
            acc[j] = a;
        }

        #pragma unroll
        for (int f = 0; f < kFC; ++f) {
            const float4 t = *reinterpret_cast<const float4*>(
                &lcat[rowdw[f] + (grp << 2)]);
            acc[0] += t.x;
            acc[1] += t.y;
            acc[2] += t.z;
            acc[3] += t.w;
        }

        #pragma unroll
        for (int j = 0; j < 4; ++j) {
            float T = acc[j];
            if (T > best)        { second = best; best = T; besti = cbase + j; }
            else if (T > second) { second = T; }
        }
    }

    // coalesced SoA result write
    ws[kOffRes + half * kN + n]          = best;
    ws[kOffRes + 2 * kN + half * kN + n] = second;
    reinterpret_cast<int*>(ws)[kOffRes + 4 * kN + half * kN + n] = besti;
}

__global__ __launch_bounds__(256) void nbc_merge(
    const int*   __restrict__ X_cat,
    const float* __restrict__ X_num,
    const float* __restrict__ class_probs,
    const float* __restrict__ cat_probs,
    const float* __restrict__ means,
    const float* __restrict__ stds,
    const float* __restrict__ ws,
    int* __restrict__ out)
{
    const int n = blockIdx.x * 256 + threadIdx.x;
    if (n >= kN) return;

    const float b0 = ws[kOffRes + n];
    const float b1 = ws[kOffRes + kN + n];
    const float s0 = ws[kOffRes + 2 * kN + n];
    const float s1 = ws[kOffRes + 3 * kN + n];
    const int   i0 = reinterpret_cast<const int*>(ws)[kOffRes + 4 * kN + n];
    const int   i1 = reinterpret_cast<const int*>(ws)[kOffRes + 5 * kN + n];

    // exact top-2 merge; ties -> half 0 (lower class index = ref first-max)
    float wb, ws2; int wi;
    if (b1 > b0) { wb = b1; wi = i1; ws2 = fmaxf(b0, s1); }
    else         { wb = b0; wi = i0; ws2 = fmaxf(b1, s0); }

    if (wb >= -86.0f && (wb - ws2) >= 8.0e-3f) {
        out[n] = wi;
        return;
    }

    // ---- rare reject: FULL exact reference sequence, all 32 classes ----
    unsigned pack[4];
    float    x[kFN];
    {
        const int4* p4 = reinterpret_cast<const int4*>(X_cat + (size_t)n * kFC);
        int4 a0 = p4[0], a1 = p4[1], a2 = p4[2], a3 = p4[3];
        pack[0] = (unsigned)a0.x | ((unsigned)a0.y << 8) |
                  ((unsigned)a0.z << 16) | ((unsigned)a0.w << 24);
        pack[1] = (unsigned)a1.x | ((unsigned)a1.y << 8) |
                  ((unsigned)a1.z << 16) | ((unsigned)a1.w << 24);
        pack[2] = (unsigned)a2.x | ((unsigned)a2.y << 8) |
                  ((unsigned)a2.z << 16) | ((unsigned)a2.w << 24);
        pack[3] = (unsigned)a3.x | ((unsigned)a3.y << 8) |
                  ((unsigned)a3.z << 16) | ((unsigned)a3.w << 24);

        const float4* q4 = reinterpret_cast<const float4*>(X_num + (size_t)n * kFN);
        float4 c0 = q4[0], c1 = q4[1], c2 = q4[2], c3 = q4[3];
        x[0]=c0.x;  x[1]=c0.y;  x[2]=c0.z;  x[3]=c0.w;
        x[4]=c1.x;  x[5]=c1.y;  x[6]=c1.z;  x[7]=c1.w;
        x[8]=c2.x;  x[9]=c2.y;  x[10]=c2.z; x[11]=c2.w;
        x[12]=c3.x; x[13]=c3.y; x[14]=c3.z; x[15]=c3.w;
    }

    const float two_pi = 2.0f * (float)M_PI;
    float bb = -INFINITY;
    int   bi = 0;
    for (int c = 0; c < kC; ++c) {
        const float* __restrict__ row = cat_probs + (size_t)c * (kFC * kV);
        float cat = row[pack[0] & 63];
        #pragma unroll
        for (int f = 1; f < kFC; ++f) {
            const int v = (pack[f >> 2] >> ((f & 3) * 8)) & 63;
            cat *= row[(f << 6) + v];
        }
        float num;
        #pragma unroll
        for (int f = 0; f < kFN; ++f) {
            float m = means[c * kFN + f];
            float s = stds [c * kFN + f];
            float inv = 1.0f / (two_pi * (s * s));
            float z = (x[f] - m) / s;              // IEEE divide
            float e = expf(-0.5f * (z * z));
            float lik = inv * e;
            num = (f == 0) ? lik : num * lik;
        }
        float pred = (class_probs[c] * cat) * num; // ((cp*cat)*num) like ref
        if (pred > bb) { bb = pred; bi = c; }      // strict > -> first max
    }
    out[n] = bi;
}

// ---- mono fallback (round-5 kernel, proven): used only if ws too small ----
__global__ __launch_bounds__(kBlock) void nbc_mono(
    const int*   __restrict__ X_cat,
    const float* __restrict__ X_num,
    const float* __restrict__ class_probs,
    const float* __restrict__ cat_probs,
    const float* __restrict__ means,
    const float* __restrict__ stds,
    const float* __restrict__ ws,
    int* __restrict__ out)
{
    __shared__ float lcat[1024 * 36];

    const int tid = threadIdx.x;
    const int n   = blockIdx.x * kBlock + tid;
    const bool active = (n < kN);

    unsigned pack[4];
    float    x[kFN];
    if (active) {
        const int4* p4 = reinterpret_cast<const int4*>(X_cat + (size_t)n * kFC);
        int4 a0 = p4[0], a1 = p4[1], a2 = p4[2], a3 = p4[3];
        pack[0] = (unsigned)a0.x | ((unsigned)a0.y << 8) |
                  ((unsigned)a0.z << 16) | ((unsigned)a0.w << 24);
        pack[1] = (unsigned)a1.x | ((unsigned)a1.y << 8) |
                  ((unsigned)a1.z << 16) | ((unsigned)a1.w << 24);
        pack[2] = (unsigned)a2.x | ((unsigned)a2.y << 8) |
                  ((unsigned)a2.z << 16) | ((unsigned)a2.w << 24);
        pack[3] = (unsigned)a3.x | ((unsigned)a3.y << 8) |
                  ((unsigned)a3.z << 16) | ((unsigned)a3.w << 24);
        const float4* q4 = reinterpret_cast<const float4*>(X_num + (size_t)n * kFN);
        float4 b0 = q4[0], b1 = q4[1], b2 = q4[2], b3 = q4[3];
        x[0]=b0.x;  x[1]=b0.y;  x[2]=b0.z;  x[3]=b0.w;
        x[4]=b1.x;  x[5]=b1.y;  x[6]=b1.z;  x[7]=b1.w;
        x[8]=b2.x;  x[9]=b2.y;  x[10]=b2.z; x[11]=b2.w;
        x[12]=b3.x; x[13]=b3.y; x[14]=b3.z; x[15]=b3.w;
    } else {
        pack[0] = pack[1] = pack[2] = pack[3] = 0u;
        #pragma unroll
        for (int f = 0; f < kFN; ++f) x[f] = 0.0f;
    }

    #pragma unroll
    for (int cg = 0; cg < 8; ++cg) {
        float4 w;
        w.x = logf(cat_probs[(size_t)(cg * 4 + 0) * 1024 + tid]);
        w.y = logf(cat_probs[(size_t)(cg * 4 + 1) * 1024 + tid]);
        w.z = logf(cat_probs[(size_t)(cg * 4 + 2) * 1024 + tid]);
        w.w = logf(cat_probs[(size_t)(cg * 4 + 3) * 1024 + tid]);
        *reinterpret_cast<float4*>(lcat + (size_t)tid * 36 + cg * 4) = w;
    }
    __syncthreads();

    if (!active) return;

    int rowdw[kFC];
    #pragma unroll
    for (int f = 0; f < kFC; ++f) {
        const int v = (pack[f >> 2] >> ((f & 3) * 8)) & 63;
        rowdw[f] = ((f << 6) + v) * 36;
    }

    const float2* __restrict__ P = reinterpret_cast<const float2*>(ws);
    const float*  __restrict__ K = ws + 1024;

    float best = -INFINITY, second = -INFINITY;
    int   besti = 0;

    #pragma unroll 1
    for (int grp = 0; grp < 8; ++grp) {
        const int cbase = grp << 2;
        float acc[4];
        #pragma unroll
        for (int j = 0; j < 4; ++j) {
            const int c = cbase + j;
            float a = K[c];
            #pragma unroll
            for (int f = 0; f < kFN; ++f) {
                float2 p = P[(c << 4) + f];
                a = fmaf(x[f], fmaf(x[f], p.x, p.y), a);
            }
            acc[j] = a;
        }
        #pragma unroll
        for (int f = 0; f < kFC; ++f) {
            const float4 t = *reinterpret_cast<const float4*>(
                &lcat[rowdw[f] + (grp << 2)]);
            acc[0] += t.x; acc[1] += t.y; acc[2] += t.z; acc[3] += t.w;
        }
        #pragma unroll
        for (int j = 0; j < 4; ++j) {
            float T = acc[j];
            if (T > best)        { second = best; best = T; besti = cbase + j; }
            else if (T > second) { second = T; }
        }
    }

    if (best >= -86.0f && (best - second) >= 8.0e-3f) {
        out[n] = besti;
        return;
    }

    const float thr    = (best >= -86.0f) ? (best - 1.6e-2f) : -INFINITY;
    const float two_pi = 2.0f * (float)M_PI;
    float bb = -INFINITY;
    int   bi = 0;
    for (int c = 0; c < kC; ++c) {
        float a = K[c];
        #pragma unroll
        for (int f = 0; f < kFN; ++f) {
            float2 p = P[(c << 4) + f];
            a = fmaf(x[f], fmaf(x[f], p.x, p.y), a);
        }
        #pragma unroll
        for (int f = 0; f < kFC; ++f) a += lcat[rowdw[f] + c];

        if (a >= thr) {
            const float* __restrict__ row = cat_probs + (size_t)c * (kFC * kV);
            float cat = row[pack[0] & 63];
            #pragma unroll
            for (int f = 1; f < kFC; ++f) {
                const int v = (pack[f >> 2] >> ((f & 3) * 8)) & 63;
                cat *= row[(f << 6) + v];
            }
            float num;
            #pragma unroll
            for (int f = 0; f < kFN; ++f) {
                float m = means[c * kFN + f];
                float s = stds [c * kFN + f];
                float inv = 1.0f / (two_pi * (s * s));
                float z = (x[f] - m) / s;
                float e = expf(-0.5f * (z * z));
                float lik = inv * e;
                num = (f == 0) ? lik : num * lik;
            }
            float pred = (class_probs[c] * cat) * num;
            if (pred > bb) { bb = pred; bi = c; }
        }
    }
    out[n] = bi;
}

extern "C" void kernel_launch(void* const* d_in, const int* in_sizes, int n_in,
                              void* d_out, int out_size, void* d_ws, size_t ws_size,
                              hipStream_t stream) {
    const int*   X_cat       = (const int*)  d_in[0];
    const float* X_num       = (const float*)d_in[1];
    const float* class_probs = (const float*)d_in[2];
    const float* cat_probs   = (const float*)d_in[3];
    const float* means       = (const float*)d_in[4];
    const float* stds        = (const float*)d_in[5];
    int*   out = (int*)d_out;
    float* ws  = (float*)d_ws;

    hipLaunchKernelGGL(nbc_prep, dim3(1), dim3(256), 0, stream,
                       class_probs, means, stds, ws);

    const int chunks = (kN + kBlock - 1) / kBlock;          // 245
    if (ws_size >= kWsNeedSplit) {
        hipLaunchKernelGGL(nbc_half, dim3(chunks * 2), dim3(kBlock), 0, stream,
                           X_cat, X_num, cat_probs, ws);
        hipLaunchKernelGGL(nbc_merge, dim3((kN + 255) / 256), dim3(256), 0, stream,
                           X_cat, X_num, class_probs, cat_probs, means, stds,
                           ws, out);
    } else {
        hipLaunchKernelGGL(nbc_mono, dim3(chunks), dim3(kBlock), 0, stream,
                           X_cat, X_num, class_probs, cat_probs, means, stds,
                           ws, out);
    }
}

// Round 7
// 190.007 us; speedup vs baseline: 1.8083x; 1.8083x over previous
//
#include <hip/hip_runtime.h>
#include <math.h>

// Problem constants (fixed by the reference).
constexpr int kN  = 250000;
constexpr int kC  = 32;
constexpr int kFC = 16;
constexpr int kFN = 16;
constexpr int kV  = 64;
constexpr int kBlock = 1024;

// Half-table row stride in dwords: 16 classes + 2 pad (72B rows).
constexpr int kRowDw = 18;

// ws layout (dwords unless noted):
//   [0..1023]    {A=-0.5/s^2, B=m/s^2} interleaved per (c,f)
//   [1024..1055] K_c (incl. folded C and log-prior)
//   [1056]       reject count (int, zeroed by prep each launch)
//   [1088 ..]    best  [2][kN] f32
//   [+2kN]       second[2][kN] f32
//   [+4kN]       besti [2][kN] u8   (2kN bytes = kN/2 dwords)
//   [..]         reject list [kN] i32
constexpr int kOffCnt  = 1056;
constexpr int kOffB    = 1088;
constexpr int kOffS    = kOffB + 2 * kN;
constexpr int kOffIBdw = kOffB + 4 * kN;           // besti, u8, 2kN bytes
constexpr int kOffList = kOffIBdw + (2 * kN + 3) / 4;
constexpr size_t kWsNeedSplit = (size_t)(kOffList + kN) * 4;   // ~5.51 MB

// ---------------------------------------------------------------------------
// Round-6 forensics: nbc_half ~25us (class-split occupancy win CONFIRMED:
// 2 blocks/CU = 32 waves/CU vs mono's 16) but nbc_merge = 250us: its
// reject path ran the full 32-class exact scoring per-lane inside mostly-
// accepted waves -> thousands of straggler waves at ~2% lane utilization.
// Round-7: merge split into a streaming accept kernel + a COMPACT reject
// list processed by a dense exact kernel (every lane a real reject).
//
// Numerics (7x-validated, unchanged): per-class T_c op order identical to
// round 5; top2(32) = exact merge of two top2(16), half-0 preferred on
// ties. Accept iff T_best >= -86 AND gap >= 8e-3 (approx bound B<=2e-3,
// gap >= 4B). Rejects (incl. deep underflow): full exact reference
// sequence over all 32 classes -> first-max semantics.
// ---------------------------------------------------------------------------

__global__ __launch_bounds__(256) void nbc_prep(
    const float* __restrict__ class_probs,
    const float* __restrict__ means,
    const float* __restrict__ stds,
    float* __restrict__ ws)
{
    const int t = threadIdx.x;
    const float two_pi = 2.0f * (float)M_PI;
    for (int i = t; i < kC * kFN; i += 256) {
        float m  = means[i];
        float s  = stds[i];
        float rs = 1.0f / s;
        ws[2 * i]     = -0.5f * rs * rs;        // A
        ws[2 * i + 1] = m * rs * rs;            // B
    }
    if (t == 0) reinterpret_cast<int*>(ws)[kOffCnt] = 0;   // reject count
    if (t < kC) {
        float k = logf(class_probs[t]);
        for (int f = 0; f < kFN; ++f) {
            float s  = stds[t * kFN + f];
            float m  = means[t * kFN + f];
            float rs = 1.0f / s;
            k += logf(1.0f / (two_pi * (s * s)));
            k += -0.5f * (m * rs) * (m * rs);   // C folded into K
        }
        ws[1024 + t] = k;
    }
}

// ---- split path: one block = (sample-chunk, class-half) ----
__global__ __launch_bounds__(kBlock) void nbc_half(
    const int*   __restrict__ X_cat,
    const float* __restrict__ X_num,
    const float* __restrict__ cat_probs,
    float* __restrict__ ws)
{
    __shared__ float lcat[1024 * kRowDw];   // [r=(f,v)][class-in-half], 72 KiB

    const int chunk = blockIdx.x >> 1;
    const int half  = blockIdx.x & 1;
    const int tid   = threadIdx.x;
    const int n     = chunk * kBlock + tid;
    const bool active = (n < kN);

    unsigned pack[4];
    float    x[kFN];
    if (active) {
        const int4* p4 = reinterpret_cast<const int4*>(X_cat + (size_t)n * kFC);
        int4 a0 = p4[0], a1 = p4[1], a2 = p4[2], a3 = p4[3];
        pack[0] = (unsigned)a0.x | ((unsigned)a0.y << 8) |
                  ((unsigned)a0.z << 16) | ((unsigned)a0.w << 24);
        pack[1] = (unsigned)a1.x | ((unsigned)a1.y << 8) |
                  ((unsigned)a1.z << 16) | ((unsigned)a1.w << 24);
        pack[2] = (unsigned)a2.x | ((unsigned)a2.y << 8) |
                  ((unsigned)a2.z << 16) | ((unsigned)a2.w << 24);
        pack[3] = (unsigned)a3.x | ((unsigned)a3.y << 8) |
                  ((unsigned)a3.z << 16) | ((unsigned)a3.w << 24);

        const float4* q4 = reinterpret_cast<const float4*>(X_num + (size_t)n * kFN);
        float4 b0 = q4[0], b1 = q4[1], b2 = q4[2], b3 = q4[3];
        x[0]=b0.x;  x[1]=b0.y;  x[2]=b0.z;  x[3]=b0.w;
        x[4]=b1.x;  x[5]=b1.y;  x[6]=b1.z;  x[7]=b1.w;
        x[8]=b2.x;  x[9]=b2.y;  x[10]=b2.z; x[11]=b2.w;
        x[12]=b3.x; x[13]=b3.y; x[14]=b3.z; x[15]=b3.w;
    } else {
        pack[0] = pack[1] = pack[2] = pack[3] = 0u;
        #pragma unroll
        for (int f = 0; f < kFN; ++f) x[f] = 0.0f;
    }

    // stage this half's log-table: thread t = row r; 16 logf; 4 b128 writes.
    {
        #pragma unroll
        for (int q = 0; q < 4; ++q) {
            float4 w;
            w.x = logf(cat_probs[(size_t)((half << 4) + q * 4 + 0) * 1024 + tid]);
            w.y = logf(cat_probs[(size_t)((half << 4) + q * 4 + 1) * 1024 + tid]);
            w.z = logf(cat_probs[(size_t)((half << 4) + q * 4 + 2) * 1024 + tid]);
            w.w = logf(cat_probs[(size_t)((half << 4) + q * 4 + 3) * 1024 + tid]);
            *reinterpret_cast<float4*>(lcat + tid * kRowDw + q * 4) = w;
        }
    }
    __syncthreads();

    if (!active) return;

    int rowdw[kFC];
    #pragma unroll
    for (int f = 0; f < kFC; ++f) {
        const int v = (pack[f >> 2] >> ((f & 3) * 8)) & 63;
        rowdw[f] = ((f << 6) + v) * kRowDw;
    }

    const float2* __restrict__ P = reinterpret_cast<const float2*>(ws); // {A,B}
    const float*  __restrict__ K = ws + 1024;

    float best = -INFINITY, second = -INFINITY;
    int   besti = 0;

    #pragma unroll 1
    for (int grp = 0; grp < 4; ++grp) {
        const int cbase = (half << 4) + (grp << 2);   // global class base
        float acc[4];

        #pragma unroll
        for (int j = 0; j < 4; ++j) {
            const int c = cbase + j;                  // wave-uniform
            float a = K[c];
            #pragma unroll
            for (int f = 0; f < kFN; ++f) {
                float2 p = P[(c << 4) + f];
                a = fmaf(x[f], fmaf(x[f], p.x, p.y), a);
            }
            acc[j] = a;
        }

        #pragma unroll
        for (int f = 0; f < kFC; ++f) {
            const float4 t = *reinterpret_cast<const float4*>(
                &lcat[rowdw[f] + (grp << 2)]);
            acc[0] += t.x;
            acc[1] += t.y;
            acc[2] += t.z;
            acc[3] += t.w;
        }

        #pragma unroll
        for (int j = 0; j < 4; ++j) {
            float T = acc[j];
            if (T > best)        { second = best; best = T; besti = cbase + j; }
            else if (T > second) { second = T; }
        }
    }

    // coalesced SoA result write (besti as u8)
    ws[kOffB + half * kN + n] = best;
    ws[kOffS + half * kN + n] = second;
    reinterpret_cast<unsigned char*>(ws)[(size_t)kOffIBdw * 4 + half * kN + n] =
        (unsigned char)besti;
}

// ---- streaming merge: accept -> out; reject -> compact list ----
__global__ __launch_bounds__(256) void nbc_merge_fast(
    float* __restrict__ ws,
    int* __restrict__ out)
{
    const int n = blockIdx.x * 256 + threadIdx.x;
    if (n >= kN) return;

    const float b0 = ws[kOffB + n];
    const float b1 = ws[kOffB + kN + n];
    const float s0 = ws[kOffS + n];
    const float s1 = ws[kOffS + kN + n];
    const unsigned char* ib =
        reinterpret_cast<const unsigned char*>(ws) + (size_t)kOffIBdw * 4;
    const int i0 = ib[n];
    const int i1 = ib[kN + n];

    // exact top-2 merge; ties -> half 0 (lower class index = ref first-max)
    float wb, ws2; int wi;
    if (b1 > b0) { wb = b1; wi = i1; ws2 = fmaxf(b0, s1); }
    else         { wb = b0; wi = i0; ws2 = fmaxf(b1, s0); }

    if (wb >= -86.0f && (wb - ws2) >= 8.0e-3f) {
        out[n] = wi;
    } else {
        int slot = atomicAdd(reinterpret_cast<int*>(ws) + kOffCnt, 1);
        reinterpret_cast<int*>(ws)[kOffList + slot] = n;
    }
}

// ---- dense exact scoring of the reject list ----
__global__ __launch_bounds__(256) void nbc_exact(
    const int*   __restrict__ X_cat,
    const float* __restrict__ X_num,
    const float* __restrict__ class_probs,
    const float* __restrict__ cat_probs,
    const float* __restrict__ means,
    const float* __restrict__ stds,
    const float* __restrict__ ws,
    int* __restrict__ out)
{
    const int total = reinterpret_cast<const int*>(ws)[kOffCnt];
    const int stride = gridDim.x * 256;
    const float two_pi = 2.0f * (float)M_PI;

    for (int i = blockIdx.x * 256 + threadIdx.x; i < total; i += stride) {
        const int n = reinterpret_cast<const int*>(ws)[kOffList + i];

        unsigned pack[4];
        float    x[kFN];
        {
            const int4* p4 = reinterpret_cast<const int4*>(X_cat + (size_t)n * kFC);
            int4 a0 = p4[0], a1 = p4[1], a2 = p4[2], a3 = p4[3];
            pack[0] = (unsigned)a0.x | ((unsigned)a0.y << 8) |
                      ((unsigned)a0.z << 16) | ((unsigned)a0.w << 24);
            pack[1] = (unsigned)a1.x | ((unsigned)a1.y << 8) |
                      ((unsigned)a1.z << 16) | ((unsigned)a1.w << 24);
            pack[2] = (unsigned)a2.x | ((unsigned)a2.y << 8) |
                      ((unsigned)a2.z << 16) | ((unsigned)a2.w << 24);
            pack[3] = (unsigned)a3.x | ((unsigned)a3.y << 8) |
                      ((unsigned)a3.z << 16) | ((unsigned)a3.w << 24);

            const float4* q4 =
                reinterpret_cast<const float4*>(X_num + (size_t)n * kFN);
            float4 c0 = q4[0], c1 = q4[1], c2 = q4[2], c3 = q4[3];
            x[0]=c0.x;  x[1]=c0.y;  x[2]=c0.z;  x[3]=c0.w;
            x[4]=c1.x;  x[5]=c1.y;  x[6]=c1.z;  x[7]=c1.w;
            x[8]=c2.x;  x[9]=c2.y;  x[10]=c2.z; x[11]=c2.w;
            x[12]=c3.x; x[13]=c3.y; x[14]=c3.z; x[15]=c3.w;
        }

        // FULL exact reference sequence, all 32 classes (validated).
        float bb = -INFINITY;
        int   bi = 0;
        for (int c = 0; c < kC; ++c) {
            const float* __restrict__ row = cat_probs + (size_t)c * (kFC * kV);
            float cat = row[pack[0] & 63];
            #pragma unroll
            for (int f = 1; f < kFC; ++f) {
                const int v = (pack[f >> 2] >> ((f & 3) * 8)) & 63;
                cat *= row[(f << 6) + v];
            }
            float num;
            #pragma unroll
            for (int f = 0; f < kFN; ++f) {
                float m = means[c * kFN + f];
                float s = stds [c * kFN + f];
                float inv = 1.0f / (two_pi * (s * s));
                float z = (x[f] - m) / s;              // IEEE divide
                float e = expf(-0.5f * (z * z));
                float lik = inv * e;
                num = (f == 0) ? lik : num * lik;
            }
            float pred = (class_probs[c] * cat) * num; // ((cp*cat)*num) like ref
            if (pred > bb) { bb = pred; bi = c; }      // strict > -> first max
        }
        out[n] = bi;
    }
}

// ---- mono fallback (round-5 kernel, proven): used only if ws too small ----
__global__ __launch_bounds__(kBlock) void nbc_mono(
    const int*   __restrict__ X_cat,
    const float* __restrict__ X_num,
    const float* __restrict__ class_probs,
    const float* __restrict__ cat_probs,
    const float* __restrict__ means,
    const float* __restrict__ stds,
    const float* __restrict__ ws,
    int* __restrict__ out)
{
    __shared__ float lcat[1024 * 36];

    const int tid = threadIdx.x;
    const int n   = blockIdx.x * kBlock + tid;
    const bool active = (n < kN);

    unsigned pack[4];
    float    x[kFN];
    if (active) {
        const int4* p4 = reinterpret_cast<const int4*>(X_cat + (size_t)n * kFC);
        int4 a0 = p4[0], a1 = p4[1], a2 = p4[2], a3 = p4[3];
        pack[0] = (unsigned)a0.x | ((unsigned)a0.y << 8) |
                  ((unsigned)a0.z << 16) | ((unsigned)a0.w << 24);
        pack[1] = (unsigned)a1.x | ((unsigned)a1.y << 8) |
                  ((unsigned)a1.z << 16) | ((unsigned)a1.w << 24);
        pack[2] = (unsigned)a2.x | ((unsigned)a2.y << 8) |
                  ((unsigned)a2.z << 16) | ((unsigned)a2.w << 24);
        pack[3] = (unsigned)a3.x | ((unsigned)a3.y << 8) |
                  ((unsigned)a3.z << 16) | ((unsigned)a3.w << 24);
        const float4* q4 = reinterpret_cast<const float4*>(X_num + (size_t)n * kFN);
        float4 b0 = q4[0], b1 = q4[1], b2 = q4[2], b3 = q4[3];
        x[0]=b0.x;  x[1]=b0.y;  x[2]=b0.z;  x[3]=b0.w;
        x[4]=b1.x;  x[5]=b1.y;  x[6]=b1.z;  x[7]=b1.w;
        x[8]=b2.x;  x[9]=b2.y;  x[10]=b2.z; x[11]=b2.w;
        x[12]=b3.x; x[13]=b3.y; x[14]=b3.z; x[15]=b3.w;
    } else {
        pack[0] = pack[1] = pack[2] = pack[3] = 0u;
        #pragma unroll
        for (int f = 0; f < kFN; ++f) x[f] = 0.0f;
    }

    #pragma unroll
    for (int cg = 0; cg < 8; ++cg) {
        float4 w;
        w.x = logf(cat_probs[(size_t)(cg * 4 + 0) * 1024 + tid]);
        w.y = logf(cat_probs[(size_t)(cg * 4 + 1) * 1024 + tid]);
        w.z = logf(cat_probs[(size_t)(cg * 4 + 2) * 1024 + tid]);
        w.w = logf(cat_probs[(size_t)(cg * 4 + 3) * 1024 + tid]);
        *reinterpret_cast<float4*>(lcat + (size_t)tid * 36 + cg * 4) = w;
    }
    __syncthreads();

    if (!active) return;

    int rowdw[kFC];
    #pragma unroll
    for (int f = 0; f < kFC; ++f) {
        const int v = (pack[f >> 2] >> ((f & 3) * 8)) & 63;
        rowdw[f] = ((f << 6) + v) * 36;
    }

    const float2* __restrict__ P = reinterpret_cast<const float2*>(ws);
    const float*  __restrict__ K = ws + 1024;

    float best = -INFINITY, second = -INFINITY;
    int   besti = 0;

    #pragma unroll 1
    for (int grp = 0; grp < 8; ++grp) {
        const int cbase = grp << 2;
        float acc[4];
        #pragma unroll
        for (int j = 0; j < 4; ++j) {
            const int c = cbase + j;
            float a = K[c];
            #pragma unroll
            for (int f = 0; f < kFN; ++f) {
                float2 p = P[(c << 4) + f];
                a = fmaf(x[f], fmaf(x[f], p.x, p.y), a);
            }
            acc[j] = a;
        }
        #pragma unroll
        for (int f = 0; f < kFC; ++f) {
            const float4 t = *reinterpret_cast<const float4*>(
                &lcat[rowdw[f] + (grp << 2)]);
            acc[0] += t.x; acc[1] += t.y; acc[2] += t.z; acc[3] += t.w;
        }
        #pragma unroll
        for (int j = 0; j < 4; ++j) {
            float T = acc[j];
            if (T > best)        { second = best; best = T; besti = cbase + j; }
            else if (T > second) { second = T; }
        }
    }

    if (best >= -86.0f && (best - second) >= 8.0e-3f) {
        out[n] = besti;
        return;
    }

    const float thr    = (best >= -86.0f) ? (best - 1.6e-2f) : -INFINITY;
    const float two_pi = 2.0f * (float)M_PI;
    float bb = -INFINITY;
    int   bi = 0;
    for (int c = 0; c < kC; ++c) {
        float a = K[c];
        #pragma unroll
        for (int f = 0; f < kFN; ++f) {
            float2 p = P[(c << 4) + f];
            a = fmaf(x[f], fmaf(x[f], p.x, p.y), a);
        }
        #pragma unroll
        for (int f = 0; f < kFC; ++f) a += lcat[rowdw[f] + c];

        if (a >= thr) {
            const float* __restrict__ row = cat_probs + (size_t)c * (kFC * kV);
            float cat = row[pack[0] & 63];
            #pragma unroll
            for (int f = 1; f < kFC; ++f) {
                const int v = (pack[f >> 2] >> ((f & 3) * 8)) & 63;
                cat *= row[(f << 6) + v];
            }
            float num;
            #pragma unroll
            for (int f = 0; f < kFN; ++f) {
                float m = means[c * kFN + f];
                float s = stds [c * kFN + f];
                float inv = 1.0f / (two_pi * (s * s));
                float z = (x[f] - m) / s;
                float e = expf(-0.5f * (z * z));
                float lik = inv * e;
                num = (f == 0) ? lik : num * lik;
            }
            float pred = (class_probs[c] * cat) * num;
            if (pred > bb) { bb = pred; bi = c; }
        }
    }
    out[n] = bi;
}

extern "C" void kernel_launch(void* const* d_in, const int* in_sizes, int n_in,
                              void* d_out, int out_size, void* d_ws, size_t ws_size,
                              hipStream_t stream) {
    const int*   X_cat       = (const int*)  d_in[0];
    const float* X_num       = (const float*)d_in[1];
    const float* class_probs = (const float*)d_in[2];
    const float* cat_probs   = (const float*)d_in[3];
    const float* means       = (const float*)d_in[4];
    const float* stds        = (const float*)d_in[5];
    int*   out = (int*)d_out;
    float* ws  = (float*)d_ws;

    hipLaunchKernelGGL(nbc_prep, dim3(1), dim3(256), 0, stream,
                       class_probs, means, stds, ws);

    const int chunks = (kN + kBlock - 1) / kBlock;          // 245
    if (ws_size >= kWsNeedSplit) {
        hipLaunchKernelGGL(nbc_half, dim3(chunks * 2), dim3(kBlock), 0, stream,
                           X_cat, X_num, cat_probs, ws);
        hipLaunchKernelGGL(nbc_merge_fast, dim3((kN + 255) / 256), dim3(256),
                           0, stream, ws, out);
        hipLaunchKernelGGL(nbc_exact, dim3(512), dim3(256), 0, stream,
                           X_cat, X_num, class_probs, cat_probs, means, stds,
                           ws, out);
    } else {
        hipLaunchKernelGGL(nbc_mono, dim3(chunks), dim3(kBlock), 0, stream,
                           X_cat, X_num, class_probs, cat_probs, means, stds,
                           ws, out);
    }
}

// Round 8
// 130.731 us; speedup vs baseline: 2.6283x; 1.4534x over previous
//
#include <hip/hip_runtime.h>
#include <math.h>

// Problem constants (fixed by the reference).
constexpr int kN  = 250000;
constexpr int kC  = 32;
constexpr int kFC = 16;
constexpr int kFN = 16;
constexpr int kV  = 64;
constexpr int kBlock = 1024;

// Half-table row stride in dwords: 16 classes + 2 pad (72B rows).
constexpr int kRowDw = 18;

// ws layout (dwords unless noted):
//   [0..1023]    {A=-0.5/s^2, B=m/s^2} interleaved per (c,f)
//   [1024..1055] K_c (incl. folded C and log-prior)
//   [1056]       reject count (int, zeroed by prep each launch)
//   [1088 ..]    best  [2][kN] f32
//   [+2kN]       second[2][kN] f32
//   [+4kN]       besti [2][kN] u8   (2kN bytes = kN/2 dwords)
//   [..]         reject list [kN] i32
constexpr int kOffCnt  = 1056;
constexpr int kOffB    = 1088;
constexpr int kOffS    = kOffB + 2 * kN;
constexpr int kOffIBdw = kOffB + 4 * kN;           // besti, u8, 2kN bytes
constexpr int kOffList = kOffIBdw + (2 * kN + 3) / 4;
constexpr size_t kWsNeedSplit = (size_t)(kOffList + kN) * 4;   // ~5.51 MB

// ---------------------------------------------------------------------------
// Round-7 forensics: compact-list structure works (half ~25us, merge ~5us)
// but nbc_exact = 69us at 0.55% VALUBusy / 0.56% occupancy: each reject
// thread ran a ~5k-inst SERIAL chain (32 classes x 16 sequential IEEE
// div+expf + scattered gathers) with nothing to hide the latency.
// Round-8: CLASS-PER-LANE exact. A 64-lane wave = 2 rejects x 32 classes;
// per-lane runs ONE class's bit-exact reference sequence; a 5-step
// shfl_xor butterfly reduces (pred, class) with max-value/min-index-tie
// = jnp.argmax first-max semantics (all-zero underflow tie -> class 0).
// Chain 32x shorter, parallelism 32x higher.
//
// Numerics (7x-validated, unchanged): per-class T_c op order identical to
// round 5; top2(32) = exact merge of two top2(16), half-0 preferred on
// ties. Accept iff T_best >= -86 AND gap >= 8e-3 (approx bound B<=2e-3,
// gap >= 4B). Rejects: full exact reference sequence per class.
// ---------------------------------------------------------------------------

__global__ __launch_bounds__(256) void nbc_prep(
    const float* __restrict__ class_probs,
    const float* __restrict__ means,
    const float* __restrict__ stds,
    float* __restrict__ ws)
{
    const int t = threadIdx.x;
    const float two_pi = 2.0f * (float)M_PI;
    for (int i = t; i < kC * kFN; i += 256) {
        float m  = means[i];
        float s  = stds[i];
        float rs = 1.0f / s;
        ws[2 * i]     = -0.5f * rs * rs;        // A
        ws[2 * i + 1] = m * rs * rs;            // B
    }
    if (t == 0) reinterpret_cast<int*>(ws)[kOffCnt] = 0;   // reject count
    if (t < kC) {
        float k = logf(class_probs[t]);
        for (int f = 0; f < kFN; ++f) {
            float s  = stds[t * kFN + f];
            float m  = means[t * kFN + f];
            float rs = 1.0f / s;
            k += logf(1.0f / (two_pi * (s * s)));
            k += -0.5f * (m * rs) * (m * rs);   // C folded into K
        }
        ws[1024 + t] = k;
    }
}

// ---- split path: one block = (sample-chunk, class-half) ----
__global__ __launch_bounds__(kBlock) void nbc_half(
    const int*   __restrict__ X_cat,
    const float* __restrict__ X_num,
    const float* __restrict__ cat_probs,
    float* __restrict__ ws)
{
    __shared__ float lcat[1024 * kRowDw];   // [r=(f,v)][class-in-half], 72 KiB

    const int chunk = blockIdx.x >> 1;
    const int half  = blockIdx.x & 1;
    const int tid   = threadIdx.x;
    const int n     = chunk * kBlock + tid;
    const bool active = (n < kN);

    unsigned pack[4];
    float    x[kFN];
    if (active) {
        const int4* p4 = reinterpret_cast<const int4*>(X_cat + (size_t)n * kFC);
        int4 a0 = p4[0], a1 = p4[1], a2 = p4[2], a3 = p4[3];
        pack[0] = (unsigned)a0.x | ((unsigned)a0.y << 8) |
                  ((unsigned)a0.z << 16) | ((unsigned)a0.w << 24);
        pack[1] = (unsigned)a1.x | ((unsigned)a1.y << 8) |
                  ((unsigned)a1.z << 16) | ((unsigned)a1.w << 24);
        pack[2] = (unsigned)a2.x | ((unsigned)a2.y << 8) |
                  ((unsigned)a2.z << 16) | ((unsigned)a2.w << 24);
        pack[3] = (unsigned)a3.x | ((unsigned)a3.y << 8) |
                  ((unsigned)a3.z << 16) | ((unsigned)a3.w << 24);

        const float4* q4 = reinterpret_cast<const float4*>(X_num + (size_t)n * kFN);
        float4 b0 = q4[0], b1 = q4[1], b2 = q4[2], b3 = q4[3];
        x[0]=b0.x;  x[1]=b0.y;  x[2]=b0.z;  x[3]=b0.w;
        x[4]=b1.x;  x[5]=b1.y;  x[6]=b1.z;  x[7]=b1.w;
        x[8]=b2.x;  x[9]=b2.y;  x[10]=b2.z; x[11]=b2.w;
        x[12]=b3.x; x[13]=b3.y; x[14]=b3.z; x[15]=b3.w;
    } else {
        pack[0] = pack[1] = pack[2] = pack[3] = 0u;
        #pragma unroll
        for (int f = 0; f < kFN; ++f) x[f] = 0.0f;
    }

    // stage this half's log-table: thread t = row r; 16 logf; 4 b128 writes.
    {
        #pragma unroll
        for (int q = 0; q < 4; ++q) {
            float4 w;
            w.x = logf(cat_probs[(size_t)((half << 4) + q * 4 + 0) * 1024 + tid]);
            w.y = logf(cat_probs[(size_t)((half << 4) + q * 4 + 1) * 1024 + tid]);
            w.z = logf(cat_probs[(size_t)((half << 4) + q * 4 + 2) * 1024 + tid]);
            w.w = logf(cat_probs[(size_t)((half << 4) + q * 4 + 3) * 1024 + tid]);
            *reinterpret_cast<float4*>(lcat + tid * kRowDw + q * 4) = w;
        }
    }
    __syncthreads();

    if (!active) return;

    int rowdw[kFC];
    #pragma unroll
    for (int f = 0; f < kFC; ++f) {
        const int v = (pack[f >> 2] >> ((f & 3) * 8)) & 63;
        rowdw[f] = ((f << 6) + v) * kRowDw;
    }

    const float2* __restrict__ P = reinterpret_cast<const float2*>(ws); // {A,B}
    const float*  __restrict__ K = ws + 1024;

    float best = -INFINITY, second = -INFINITY;
    int   besti = 0;

    #pragma unroll 1
    for (int grp = 0; grp < 4; ++grp) {
        const int cbase = (half << 4) + (grp << 2);   // global class base
        float acc[4];

        #pragma unroll
        for (int j = 0; j < 4; ++j) {
            const int c = cbase + j;                  // wave-uniform
            float a = K[c];
            #pragma unroll
            for (int f = 0; f < kFN; ++f) {
                float2 p = P[(c << 4) + f];
                a = fmaf(x[f], fmaf(x[f], p.x, p.y), a);
            }
            acc[j] = a;
        }

        #pragma unroll
        for (int f = 0; f < kFC; ++f) {
            const float4 t = *reinterpret_cast<const float4*>(
                &lcat[rowdw[f] + (grp << 2)]);
            acc[0] += t.x;
            acc[1] += t.y;
            acc[2] += t.z;
            acc[3] += t.w;
        }

        #pragma unroll
        for (int j = 0; j < 4; ++j) {
            float T = acc[j];
            if (T > best)        { second = best; best = T; besti = cbase + j; }
            else if (T > second) { second = T; }
        }
    }

    // coalesced SoA result write (besti as u8)
    ws[kOffB + half * kN + n] = best;
    ws[kOffS + half * kN + n] = second;
    reinterpret_cast<unsigned char*>(ws)[(size_t)kOffIBdw * 4 + half * kN + n] =
        (unsigned char)besti;
}

// ---- streaming merge: accept -> out; reject -> compact list ----
__global__ __launch_bounds__(256) void nbc_merge_fast(
    float* __restrict__ ws,
    int* __restrict__ out)
{
    const int n = blockIdx.x * 256 + threadIdx.x;
    if (n >= kN) return;

    const float b0 = ws[kOffB + n];
    const float b1 = ws[kOffB + kN + n];
    const float s0 = ws[kOffS + n];
    const float s1 = ws[kOffS + kN + n];
    const unsigned char* ib =
        reinterpret_cast<const unsigned char*>(ws) + (size_t)kOffIBdw * 4;
    const int i0 = ib[n];
    const int i1 = ib[kN + n];

    // exact top-2 merge; ties -> half 0 (lower class index = ref first-max)
    float wb, ws2; int wi;
    if (b1 > b0) { wb = b1; wi = i1; ws2 = fmaxf(b0, s1); }
    else         { wb = b0; wi = i0; ws2 = fmaxf(b1, s0); }

    if (wb >= -86.0f && (wb - ws2) >= 8.0e-3f) {
        out[n] = wi;
    } else {
        int slot = atomicAdd(reinterpret_cast<int*>(ws) + kOffCnt, 1);
        reinterpret_cast<int*>(ws)[kOffList + slot] = n;
    }
}

// ---- dense exact scoring of the reject list: ONE CLASS PER LANE ----
// 64-lane wave = 2 rejects; lane&31 = class; 5-step shfl_xor butterfly
// reduces (pred, class) with max-value / min-index-on-tie = first max.
__global__ __launch_bounds__(256) void nbc_exact(
    const int*   __restrict__ X_cat,
    const float* __restrict__ X_num,
    const float* __restrict__ class_probs,
    const float* __restrict__ cat_probs,
    const float* __restrict__ means,
    const float* __restrict__ stds,
    const float* __restrict__ ws,
    int* __restrict__ out)
{
    const int total  = reinterpret_cast<const int*>(ws)[kOffCnt];
    const int c      = threadIdx.x & 31;                 // this lane's class
    const int gid0   = (blockIdx.x * 256 + threadIdx.x) >> 5;
    const int gstride = (gridDim.x * 256) >> 5;
    const float two_pi = 2.0f * (float)M_PI;

    for (int g = gid0; g < total; g += gstride) {
        const int n = reinterpret_cast<const int*>(ws)[kOffList + g];

        unsigned pack[4];
        float    x[kFN];
        {
            const int4* p4 = reinterpret_cast<const int4*>(X_cat + (size_t)n * kFC);
            int4 a0 = p4[0], a1 = p4[1], a2 = p4[2], a3 = p4[3];
            pack[0] = (unsigned)a0.x | ((unsigned)a0.y << 8) |
                      ((unsigned)a0.z << 16) | ((unsigned)a0.w << 24);
            pack[1] = (unsigned)a1.x | ((unsigned)a1.y << 8) |
                      ((unsigned)a1.z << 16) | ((unsigned)a1.w << 24);
            pack[2] = (unsigned)a2.x | ((unsigned)a2.y << 8) |
                      ((unsigned)a2.z << 16) | ((unsigned)a2.w << 24);
            pack[3] = (unsigned)a3.x | ((unsigned)a3.y << 8) |
                      ((unsigned)a3.z << 16) | ((unsigned)a3.w << 24);

            const float4* q4 =
                reinterpret_cast<const float4*>(X_num + (size_t)n * kFN);
            float4 c0 = q4[0], c1 = q4[1], c2 = q4[2], c3 = q4[3];
            x[0]=c0.x;  x[1]=c0.y;  x[2]=c0.z;  x[3]=c0.w;
            x[4]=c1.x;  x[5]=c1.y;  x[6]=c1.z;  x[7]=c1.w;
            x[8]=c2.x;  x[9]=c2.y;  x[10]=c2.z; x[11]=c2.w;
            x[12]=c3.x; x[13]=c3.y; x[14]=c3.z; x[15]=c3.w;
        }

        // Exact reference sequence for THIS lane's class (validated op order).
        const float* __restrict__ row = cat_probs + (size_t)c * (kFC * kV);
        float cat = row[pack[0] & 63];
        #pragma unroll
        for (int f = 1; f < kFC; ++f) {
            const int v = (pack[f >> 2] >> ((f & 3) * 8)) & 63;
            cat *= row[(f << 6) + v];
        }
        float num;
        #pragma unroll
        for (int f = 0; f < kFN; ++f) {
            float m = means[c * kFN + f];
            float s = stds [c * kFN + f];
            float inv = 1.0f / (two_pi * (s * s));
            float z = (x[f] - m) / s;              // IEEE divide
            float e = expf(-0.5f * (z * z));
            float lik = inv * e;
            num = (f == 0) ? lik : num * lik;
        }
        float pred = (class_probs[c] * cat) * num; // ((cp*cat)*num) like ref

        // 32-lane argmax reduce: max value, min class index on ties.
        float bb = pred;
        int   bi = c;
        #pragma unroll
        for (int m2 = 1; m2 < 32; m2 <<= 1) {
            float ov = __shfl_xor(bb, m2);
            int   oi = __shfl_xor(bi, m2);
            if (ov > bb || (ov == bb && oi < bi)) { bb = ov; bi = oi; }
        }
        if (c == 0) out[n] = bi;                   // first-max semantics
    }
}

// ---- mono fallback (round-5 kernel, proven): used only if ws too small ----
__global__ __launch_bounds__(kBlock) void nbc_mono(
    const int*   __restrict__ X_cat,
    const float* __restrict__ X_num,
    const float* __restrict__ class_probs,
    const float* __restrict__ cat_probs,
    const float* __restrict__ means,
    const float* __restrict__ stds,
    const float* __restrict__ ws,
    int* __restrict__ out)
{
    __shared__ float lcat[1024 * 36];

    const int tid = threadIdx.x;
    const int n   = blockIdx.x * kBlock + tid;
    const bool active = (n < kN);

    unsigned pack[4];
    float    x[kFN];
    if (active) {
        const int4* p4 = reinterpret_cast<const int4*>(X_cat + (size_t)n * kFC);
        int4 a0 = p4[0], a1 = p4[1], a2 = p4[2], a3 = p4[3];
        pack[0] = (unsigned)a0.x | ((unsigned)a0.y << 8) |
                  ((unsigned)a0.z << 16) | ((unsigned)a0.w << 24);
        pack[1] = (unsigned)a1.x | ((unsigned)a1.y << 8) |
                  ((unsigned)a1.z << 16) | ((unsigned)a1.w << 24);
        pack[2] = (unsigned)a2.x | ((unsigned)a2.y << 8) |
                  ((unsigned)a2.z << 16) | ((unsigned)a2.w << 24);
        pack[3] = (unsigned)a3.x | ((unsigned)a3.y << 8) |
                  ((unsigned)a3.z << 16) | ((unsigned)a3.w << 24);
        const float4* q4 = reinterpret_cast<const float4*>(X_num + (size_t)n * kFN);
        float4 b0 = q4[0], b1 = q4[1], b2 = q4[2], b3 = q4[3];
        x[0]=b0.x;  x[1]=b0.y;  x[2]=b0.z;  x[3]=b0.w;
        x[4]=b1.x;  x[5]=b1.y;  x[6]=b1.z;  x[7]=b1.w;
        x[8]=b2.x;  x[9]=b2.y;  x[10]=b2.z; x[11]=b2.w;
        x[12]=b3.x; x[13]=b3.y; x[14]=b3.z; x[15]=b3.w;
    } else {
        pack[0] = pack[1] = pack[2] = pack[3] = 0u;
        #pragma unroll
        for (int f = 0; f < kFN; ++f) x[f] = 0.0f;
    }

    #pragma unroll
    for (int cg = 0; cg < 8; ++cg) {
        float4 w;
        w.x = logf(cat_probs[(size_t)(cg * 4 + 0) * 1024 + tid]);
        w.y = logf(cat_probs[(size_t)(cg * 4 + 1) * 1024 + tid]);
        w.z = logf(cat_probs[(size_t)(cg * 4 + 2) * 1024 + tid]);
        w.w = logf(cat_probs[(size_t)(cg * 4 + 3) * 1024 + tid]);
        *reinterpret_cast<float4*>(lcat + (size_t)tid * 36 + cg * 4) = w;
    }
    __syncthreads();

    if (!active) return;

    int rowdw[kFC];
    #pragma unroll
    for (int f = 0; f < kFC; ++f) {
        const int v = (pack[f >> 2] >> ((f & 3) * 8)) & 63;
        rowdw[f] = ((f << 6) + v) * 36;
    }

    const float2* __restrict__ P = reinterpret_cast<const float2*>(ws);
    const float*  __restrict__ K = ws + 1024;

    float best = -INFINITY, second = -INFINITY;
    int   besti = 0;

    #pragma unroll 1
    for (int grp = 0; grp < 8; ++grp) {
        const int cbase = grp << 2;
        float acc[4];
        #pragma unroll
        for (int j = 0; j < 4; ++j) {
            const int c = cbase + j;
            float a = K[c];
            #pragma unroll
            for (int f = 0; f < kFN; ++f) {
                float2 p = P[(c << 4) + f];
                a = fmaf(x[f], fmaf(x[f], p.x, p.y), a);
            }
            acc[j] = a;
        }
        #pragma unroll
        for (int f = 0; f < kFC; ++f) {
            const float4 t = *reinterpret_cast<const float4*>(
                &lcat[rowdw[f] + (grp << 2)]);
            acc[0] += t.x; acc[1] += t.y; acc[2] += t.z; acc[3] += t.w;
        }
        #pragma unroll
        for (int j = 0; j < 4; ++j) {
            float T = acc[j];
            if (T > best)        { second = best; best = T; besti = cbase + j; }
            else if (T > second) { second = T; }
        }
    }

    if (best >= -86.0f && (best - second) >= 8.0e-3f) {
        out[n] = besti;
        return;
    }

    const float thr    = (best >= -86.0f) ? (best - 1.6e-2f) : -INFINITY;
    const float two_pi = 2.0f * (float)M_PI;
    float bb = -INFINITY;
    int   bi = 0;
    for (int c = 0; c < kC; ++c) {
        float a = K[c];
        #pragma unroll
        for (int f = 0; f < kFN; ++f) {
            float2 p = P[(c << 4) + f];
            a = fmaf(x[f], fmaf(x[f], p.x, p.y), a);
        }
        #pragma unroll
        for (int f = 0; f < kFC; ++f) a += lcat[rowdw[f] + c];

        if (a >= thr) {
            const float* __restrict__ row = cat_probs + (size_t)c * (kFC * kV);
            float cat = row[pack[0] & 63];
            #pragma unroll
            for (int f = 1; f < kFC; ++f) {
                const int v = (pack[f >> 2] >> ((f & 3) * 8)) & 63;
                cat *= row[(f << 6) + v];
            }
            float num;
            #pragma unroll
            for (int f = 0; f < kFN; ++f) {
                float m = means[c * kFN + f];
                float s = stds [c * kFN + f];
                float inv = 1.0f / (two_pi * (s * s));
                float z = (x[f] - m) / s;
                float e = expf(-0.5f * (z * z));
                float lik = inv * e;
                num = (f == 0) ? lik : num * lik;
            }
            float pred = (class_probs[c] * cat) * num;
            if (pred > bb) { bb = pred; bi = c; }
        }
    }
    out[n] = bi;
}

extern "C" void kernel_launch(void* const* d_in, const int* in_sizes, int n_in,
                              void* d_out, int out_size, void* d_ws, size_t ws_size,
                              hipStream_t stream) {
    const int*   X_cat       = (const int*)  d_in[0];
    const float* X_num       = (const float*)d_in[1];
    const float* class_probs = (const float*)d_in[2];
    const float* cat_probs   = (const float*)d_in[3];
    const float* means       = (const float*)d_in[4];
    const float* stds        = (const float*)d_in[5];
    int*   out = (int*)d_out;
    float* ws  = (float*)d_ws;

    hipLaunchKernelGGL(nbc_prep, dim3(1), dim3(256), 0, stream,
                       class_probs, means, stds, ws);

    const int chunks = (kN + kBlock - 1) / kBlock;          // 245
    if (ws_size >= kWsNeedSplit) {
        hipLaunchKernelGGL(nbc_half, dim3(chunks * 2), dim3(kBlock), 0, stream,
                           X_cat, X_num, cat_probs, ws);
        hipLaunchKernelGGL(nbc_merge_fast, dim3((kN + 255) / 256), dim3(256),
                           0, stream, ws, out);
        hipLaunchKernelGGL(nbc_exact, dim3(2048), dim3(256), 0, stream,
                           X_cat, X_num, class_probs, cat_probs, means, stds,
                           ws, out);
    } else {
        hipLaunchKernelGGL(nbc_mono, dim3(chunks), dim3(kBlock), 0, stream,
                           X_cat, X_num, class_probs, cat_probs, means, stds,
                           ws, out);
    }
}